// Round 8
// baseline (206.609 us; speedup 1.0000x reference)
//
#include <hip/hip_runtime.h>
#include <hip/hip_bf16.h>

#define B_  4
#define S_  2048
#define D_  768
#define H_  12
#define DH_ 64

typedef __bf16 bf16;
typedef __attribute__((ext_vector_type(8))) __bf16 bf16x8;
typedef __attribute__((ext_vector_type(4))) __bf16 bf16x4;
typedef __attribute__((ext_vector_type(4))) float floatx4;
typedef __attribute__((ext_vector_type(16))) float floatx16;

__device__ __forceinline__ void load_lds16(const bf16* g, bf16* l) {
    __builtin_amdgcn_global_load_lds((const __attribute__((address_space(1))) void*)g,
                                     (__attribute__((address_space(3))) void*)l, 16, 0, 0);
}

// pack two f32 -> packed bf16 pair (round-half-up: bias + v_perm, 3 ops)
__device__ __forceinline__ unsigned pack2(float a, float b) {
    unsigned ua = __builtin_bit_cast(unsigned, a) + 0x8000u;
    unsigned ub = __builtin_bit_cast(unsigned, b) + 0x8000u;
    return __builtin_amdgcn_perm(ub, ua, 0x07060302);
}

// 128-row q-tiles (qt2 0..15); kt-tiles of 64 keys, chunks of <=8 kt-tiles.
__device__ __forceinline__ int chunk_off2(int qt2) {
    if (qt2 < 4)  return qt2;
    if (qt2 < 8)  return 4 + 2 * (qt2 - 4);
    if (qt2 < 12) return 12 + 3 * (qt2 - 8);
    return 24 + 4 * (qt2 - 12);
}

// ---------------- fp32 -> bf16 conversion (vectorized) ----------------
__global__ __launch_bounds__(256) void cvt_f32_bf16(const float* __restrict__ in,
                                                    bf16* __restrict__ out, int n4) {
    int i = blockIdx.x * 256 + threadIdx.x;
    if (i < n4) {
        float4 v = ((const float4*)in)[i];
        bf16x4 o;
        o[0] = (bf16)v.x; o[1] = (bf16)v.y; o[2] = (bf16)v.z; o[3] = (bf16)v.w;
        *(bf16x4*)(out + (size_t)i * 4) = o;
    }
}

// ---------------- W transpose: W[k][n] f32 -> Wt[n][k] bf16 ----------------
__global__ __launch_bounds__(256) void w_transpose(const float* __restrict__ w0,
                                                   const float* __restrict__ w1,
                                                   const float* __restrict__ w2,
                                                   bf16* __restrict__ Wt)
{
    const int which = blockIdx.z;
    const float* W = (which == 0) ? w0 : (which == 1 ? w1 : w2);
    bf16* dst = Wt + (size_t)which * D_ * D_;
    __shared__ bf16 t[64 * 72];
    const int k0 = blockIdx.x * 64, n0 = blockIdx.y * 64;
    const int tid = threadIdx.x;
    {
        int r = tid >> 2;
        int c0 = (tid & 3) * 16;
        #pragma unroll
        for (int q = 0; q < 4; q++) {
            float4 v = *(const float4*)(W + (size_t)(k0 + r) * D_ + n0 + c0 + q * 4);
            t[(c0 + q * 4 + 0) * 72 + r] = (bf16)v.x;
            t[(c0 + q * 4 + 1) * 72 + r] = (bf16)v.y;
            t[(c0 + q * 4 + 2) * 72 + r] = (bf16)v.z;
            t[(c0 + q * 4 + 3) * 72 + r] = (bf16)v.w;
        }
    }
    __syncthreads();
    {
        int n = tid >> 3, seg = tid & 7;
        *(bf16x8*)(dst + (size_t)(n0 + n) * D_ + k0 + seg * 8) =
            *(const bf16x8*)(t + n * 72 + seg * 8);
        *(bf16x8*)(dst + (size_t)(n0 + n + 32) * D_ + k0 + seg * 8) =
            *(const bf16x8*)(t + (n + 32) * 72 + seg * 8);
    }
}

// ---------------- QKV projection GEMM ----------------
// 128x128 tile, BK=64, 32x32x16 MFMA. Double-buffered global_load_lds DMA:
// ONE barrier per K-iter; the vmcnt(0) drain at the barrier waits on loads
// issued a full compute-phase earlier (cheap). Unpadded XOR-swizzled LDS.
__global__ __launch_bounds__(256) void qkv_gemm(
    const bf16* __restrict__ Xb, const bf16* __restrict__ Wt,
    const float* __restrict__ bq, const float* __restrict__ bk,
    const float* __restrict__ bv, bf16* __restrict__ QKV)
{
    const int which = blockIdx.z;
    const bf16* Wm = Wt + (size_t)which * D_ * D_;
    const float* bias = (which == 0) ? bq : (which == 1 ? bk : bv);
    bf16* out = QKV + (size_t)which * B_ * H_ * S_ * DH_;

    __shared__ bf16 As[2][128 * 64];   // 16 KB each buffer
    __shared__ bf16 Bs[2][128 * 64];

    const int tid  = threadIdx.x;
    const int wave = tid >> 6, lane = tid & 63;
    const int wr = wave >> 1, wc = wave & 1;
    const int l31 = lane & 31, lh = lane >> 5;
    const int m0 = blockIdx.x * 128, n0 = blockIdx.y * 128;

    // DMA chunk map: 1024 16B-chunks per tile, 4/thread; lane-linear LDS dst
    int row_[4], off_[4], lds_[4];
    #pragma unroll
    for (int i = 0; i < 4; i++) {
        int fc = i * 256 + tid;
        int row = fc >> 3;
        row_[i] = row;
        off_[i] = ((fc & 7) ^ (row & 7)) * 8;   // XOR swizzle on global side
        lds_[i] = fc * 8;
    }

    floatx16 acc[2][2];
    #pragma unroll
    for (int mt = 0; mt < 2; mt++)
        #pragma unroll
        for (int nt = 0; nt < 2; nt++)
            #pragma unroll
            for (int e = 0; e < 16; e++) acc[mt][nt][e] = 0.f;

    // prologue: stage k0=0 into buffer 0
    #pragma unroll
    for (int i = 0; i < 4; i++) {
        load_lds16(Xb + (size_t)(m0 + row_[i]) * D_ + off_[i], &As[0][lds_[i]]);
        load_lds16(Wm + (size_t)(n0 + row_[i]) * D_ + off_[i], &Bs[0][lds_[i]]);
    }

    const int rxor = l31 & 7;
    for (int it = 0; it < 12; ++it) {
        const int cur = it & 1;
        __syncthreads();   // drains DMA into buf[cur] (1 iter old) + LDS reads of buf[cur^1]
        if (it + 1 < 12) {
            const int kn = (it + 1) * 64;
            #pragma unroll
            for (int i = 0; i < 4; i++) {
                load_lds16(Xb + (size_t)(m0 + row_[i]) * D_ + kn + off_[i], &As[cur ^ 1][lds_[i]]);
                load_lds16(Wm + (size_t)(n0 + row_[i]) * D_ + kn + off_[i], &Bs[cur ^ 1][lds_[i]]);
            }
        }
        const bf16* Ac = As[cur];
        const bf16* Bc = Bs[cur];
        #pragma unroll
        for (int s = 0; s < 4; s++) {
            const int sx = (((s << 1) | lh) ^ rxor) << 3;
            bf16x8 af[2], bfr[2];
            #pragma unroll
            for (int mt = 0; mt < 2; mt++)
                af[mt] = *(const bf16x8*)(Ac + ((wr * 64 + mt * 32 + l31) << 6) + sx);
            #pragma unroll
            for (int nt = 0; nt < 2; nt++)
                bfr[nt] = *(const bf16x8*)(Bc + ((wc * 64 + nt * 32 + l31) << 6) + sx);
            #pragma unroll
            for (int mt = 0; mt < 2; mt++)
                #pragma unroll
                for (int nt = 0; nt < 2; nt++)
                    acc[mt][nt] = __builtin_amdgcn_mfma_f32_32x32x16_bf16(
                        af[mt], bfr[nt], acc[mt][nt], 0, 0, 0);
        }
    }

    // Epilogue. 32x32 C layout: col=l31, row = rr + 8*rq + 4*lh (reg=4rq+rr).
    const float sc = (which == 0) ? 0.125f : 1.0f;   // fold 1/sqrt(DH) into Q
    #pragma unroll
    for (int mt = 0; mt < 2; mt++) {
        #pragma unroll
        for (int nt = 0; nt < 2; nt++) {
            const int n = n0 + wc * 64 + nt * 32 + l31;
            const float bv_ = bias[n];
            const int h = n >> 6, dh = n & 63;
            const int mb = m0 + wr * 64 + mt * 32 + 4 * lh;
            #pragma unroll
            for (int rq = 0; rq < 4; rq++) {
                const int m = mb + 8 * rq;
                const int b = m >> 11, s0 = m & 2047;
                if (which == 2) {
                    bf16x4 o;
                    #pragma unroll
                    for (int rr = 0; rr < 4; rr++) o[rr] = (bf16)(acc[mt][nt][4 * rq + rr] + bv_);
                    *(bf16x4*)(out + ((size_t)((b * H_ + h) * DH_ + dh)) * S_ + s0) = o;
                } else {
                    #pragma unroll
                    for (int rr = 0; rr < 4; rr++)
                        out[(((size_t)(b * H_ + h) * S_ + s0 + rr) << 6) + dh] =
                            (bf16)((acc[mt][nt][4 * rq + rr] + bv_) * sc);
                }
            }
        }
    }
}

// ---------------- Flash attention, 32x32x16 MFMA, transposed, DMA dbuf -----
// O^T = V^T P^T per 32-q wave slice; fixed-max softmax (additive partials).
// K/V tiles staged by double-buffered global_load_lds (one barrier/iter, no
// staging LDS-writes, no VGPR prefetch). XOR-swizzled unpadded tiles.
__global__ __launch_bounds__(256) void attn_chunk(const bf16* __restrict__ QKV,
                                                  float* __restrict__ out,
                                                  bf16* __restrict__ Opart,
                                                  float* __restrict__ Lpart)
{
    const int cid = 39 - blockIdx.x;   // heavy q-tiles dispatch first
    const int bh = blockIdx.y;
    const int b = bh / H_, h = bh % H_;

    int qt2, c;
    if (cid < 4)       { qt2 = cid; c = 0; }
    else if (cid < 12) { int t = cid - 4;  qt2 = 4 + (t >> 1);  c = t & 1; }
    else if (cid < 24) { int t = cid - 12; qt2 = 8 + t / 3;     c = t - 3 * (t / 3); }
    else               { int t = cid - 24; qt2 = 12 + (t >> 2); c = t & 3; }
    const int nch = (2 * qt2 + 9) >> 3;
    const int kt0 = c * 8;
    const int kt1 = min(kt0 + 7, 2 * qt2 + 1);

    const size_t MAT = (size_t)B_ * H_ * S_ * DH_;
    const bf16* Q  = QKV +           (size_t)bh * S_ * DH_;  // [s][dh], pre-scaled 1/8
    const bf16* K  = QKV + MAT +     (size_t)bh * S_ * DH_;  // [s][dh]
    const bf16* Vt = QKV + 2 * MAT + (size_t)bh * S_ * DH_;  // [dh][s]

    __shared__ bf16 Ks[2][64 * 64];   // 8 KB per buffer
    __shared__ bf16 Vs[2][64 * 64];

    const int tid  = threadIdx.x;
    const int wave = tid >> 6, lane = tid & 63;
    const int l31 = lane & 31, lh = lane >> 5;
    const int qbase = qt2 * 128;
    const int qs = qbase + wave * 32;     // wave's 32-q slice
    const int q = qs + l31;               // this lane's q column

    // DMA chunk map: 512 16B-chunks per tile, 2/thread
    int srow_[2], soff_[2], slds_[2];
    #pragma unroll
    for (int i = 0; i < 2; i++) {
        int fc = i * 256 + tid;
        int row = fc >> 3;
        srow_[i] = row;
        soff_[i] = ((fc & 7) ^ (row & 7)) * 8;
        slds_[i] = fc * 8;
    }

    // Q B-frags for all 4 ksteps, persistent across the kt loop.
    bf16x8 qf[4];
    {
        const bf16* qrow = Q + (size_t)q * DH_ + lh * 8;
        #pragma unroll
        for (int s = 0; s < 4; s++) qf[s] = *(const bf16x8*)(qrow + s * 16);
    }

    floatx16 accO[2];   // O^T: dh-tile dt -> rows dt*32+rho, col q
    #pragma unroll
    for (int dt = 0; dt < 2; dt++)
        #pragma unroll
        for (int e = 0; e < 16; e++) accO[dt][e] = 0.f;
    float lsum[4] = {0.f, 0.f, 0.f, 0.f};   // 4 independent add chains

    // prologue: stage kt0 into buffer 0
    #pragma unroll
    for (int i = 0; i < 2; i++) {
        load_lds16(K + ((size_t)(kt0 * 64 + srow_[i]) << 6) + soff_[i], &Ks[0][slds_[i]]);
        load_lds16(Vt + (size_t)srow_[i] * S_ + kt0 * 64 + soff_[i], &Vs[0][slds_[i]]);
    }

    const int rxor = l31 & 7;
    for (int kt = kt0; kt <= kt1; ++kt) {
        const int cur = (kt - kt0) & 1;
        __syncthreads();   // drains DMA into buf[cur] + reads of buf[cur^1]
        if (kt < kt1) {
            #pragma unroll
            for (int i = 0; i < 2; i++) {
                load_lds16(K + ((size_t)((kt + 1) * 64 + srow_[i]) << 6) + soff_[i],
                           &Ks[cur ^ 1][slds_[i]]);
                load_lds16(Vt + (size_t)srow_[i] * S_ + (kt + 1) * 64 + soff_[i],
                           &Vs[cur ^ 1][slds_[i]]);
            }
        }
        const bf16* Kc = Ks[cur];
        const bf16* Vc = Vs[cur];

        const bool domask = (kt * 64 + 63 > qs);   // wave-uniform

        #pragma unroll
        for (int kk = 0; kk < 2; kk++) {
            // S^T = K Q^T for this 32-key tile
            floatx16 accS;
            #pragma unroll
            for (int e = 0; e < 16; e++) accS[e] = 0.f;
            #pragma unroll
            for (int s = 0; s < 4; s++) {
                const int sx = (((s << 1) | lh) ^ rxor) << 3;
                bf16x8 kf = *(const bf16x8*)(Kc + ((kk * 32 + l31) << 6) + sx);
                accS = __builtin_amdgcn_mfma_f32_32x32x16_bf16(kf, qf[s], accS, 0, 0, 0);
            }

            // p = exp(s); pack to bf16 pairs; mask only on diagonal tiles
            unsigned pk1[4], pk2[4];
            if (domask) {
                const int keyb = kt * 64 + kk * 32 + 4 * lh;
                #pragma unroll
                for (int rq = 0; rq < 4; rq++) {
                    float p[4];
                    #pragma unroll
                    for (int rr = 0; rr < 4; rr++) {
                        float v = __expf(accS[4 * rq + rr]);
                        if (keyb + 8 * rq + rr > q) v = 0.f;
                        p[rr] = v;
                        lsum[rq] += v;
                    }
                    pk1[rq] = pack2(p[0], p[1]);
                    pk2[rq] = pack2(p[2], p[3]);
                }
            } else {
                #pragma unroll
                for (int rq = 0; rq < 4; rq++) {
                    float p[4];
                    #pragma unroll
                    for (int rr = 0; rr < 4; rr++) {
                        float v = __expf(accS[4 * rq + rr]);
                        p[rr] = v;
                        lsum[rq] += v;
                    }
                    pk1[rq] = pack2(p[0], p[1]);
                    pk2[rq] = pack2(p[2], p[3]);
                }
            }

            // PV for this kk's two ksteps: C->B-frag via shfl_xor(32)+selects
            #pragma unroll
            for (int sl = 0; sl < 2; sl++) {
                const int s = kk * 2 + sl;
                unsigned sendA = lh ? pk1[2 * sl] : pk1[2 * sl + 1];
                unsigned sendB = lh ? pk2[2 * sl] : pk2[2 * sl + 1];
                unsigned recvA = __shfl_xor(sendA, 32, 64);
                unsigned recvB = __shfl_xor(sendB, 32, 64);
                uint4 w;
                w.x = lh ? recvA : pk1[2 * sl];
                w.y = lh ? recvB : pk2[2 * sl];
                w.z = lh ? pk1[2 * sl + 1] : recvA;
                w.w = lh ? pk2[2 * sl + 1] : recvB;
                bf16x8 ptf = __builtin_bit_cast(bf16x8, w);
                const int sx = (((s << 1) | lh) ^ rxor) << 3;
                #pragma unroll
                for (int dt = 0; dt < 2; dt++) {
                    bf16x8 vf = *(const bf16x8*)(Vc + ((dt * 32 + l31) << 6) + sx);
                    accO[dt] = __builtin_amdgcn_mfma_f32_32x32x16_bf16(vf, ptf, accO[dt], 0, 0, 0);
                }
            }
        }
    }

    // complete the row sum: own half + partner half
    const float Lr = (lsum[0] + lsum[1]) + (lsum[2] + lsum[3]);
    const float L = Lr + __shfl_xor(Lr, 32, 64);

    if (nch == 1) {
        const float inv = 1.0f / L;
        float* orow = out + (size_t)(b * S_ + q) * D_ + h * DH_;
        #pragma unroll
        for (int dt = 0; dt < 2; dt++)
            #pragma unroll
            for (int rq = 0; rq < 4; rq++) {
                float4 o;
                o.x = accO[dt][4 * rq + 0] * inv; o.y = accO[dt][4 * rq + 1] * inv;
                o.z = accO[dt][4 * rq + 2] * inv; o.w = accO[dt][4 * rq + 3] * inv;
                *(float4*)(orow + dt * 32 + 8 * rq + 4 * lh) = o;
            }
    } else {
        const int chunk = bh * 40 + chunk_off2(qt2) + c;
        bf16* obase = Opart + (size_t)chunk * 8192 + (wave * 32 + l31) * 64;
        #pragma unroll
        for (int dt = 0; dt < 2; dt++)
            #pragma unroll
            for (int rq = 0; rq < 4; rq++) {
                bf16x4 o;
                #pragma unroll
                for (int rr = 0; rr < 4; rr++) o[rr] = (bf16)accO[dt][4 * rq + rr];
                *(bf16x4*)(obase + dt * 32 + 8 * rq + 4 * lh) = o;
            }
        if (lh == 0) Lpart[chunk * 128 + wave * 32 + l31] = L;
    }
}

// ---------------- reduce: sum chunk partials, normalize, write out ----------
__global__ __launch_bounds__(256) void attn_reduce(const bf16* __restrict__ Opart,
                                                   const float* __restrict__ Lpart,
                                                   float* __restrict__ out)
{
    const int qt2 = 4 + blockIdx.x;   // 4..15
    const int bh = blockIdx.y;
    const int b = bh / H_, h = bh % H_;
    const int nch = (2 * qt2 + 9) >> 3;   // 2..4
    const int cb = bh * 40 + chunk_off2(qt2);

    const int e = threadIdx.x;
    const int ql = e >> 1, dh0 = (e & 1) * 32;

    float o[32];
    #pragma unroll
    for (int i = 0; i < 32; i++) o[i] = 0.f;
    float l = 0.f;

    for (int cidx = 0; cidx < nch; cidx++) {
        const bf16* p = Opart + (size_t)(cb + cidx) * 8192 + ql * 64 + dh0;
        #pragma unroll
        for (int m = 0; m < 4; m++) {
            bf16x8 v = *(const bf16x8*)(p + m * 8);
            #pragma unroll
            for (int k = 0; k < 8; k++) o[m * 8 + k] += (float)v[k];
        }
        l += Lpart[(cb + cidx) * 128 + ql];
    }
    float inv = 1.0f / l;
    float* orow = out + (size_t)(b * S_ + qt2 * 128 + ql) * D_ + h * DH_ + dh0;
    #pragma unroll
    for (int m = 0; m < 8; m++) {
        float4 v;
        v.x = o[m * 4 + 0] * inv; v.y = o[m * 4 + 1] * inv;
        v.z = o[m * 4 + 2] * inv; v.w = o[m * 4 + 3] * inv;
        *(float4*)(orow + m * 4) = v;
    }
}

extern "C" void kernel_launch(void* const* d_in, const int* in_sizes, int n_in,
                              void* d_out, int out_size, void* d_ws, size_t ws_size,
                              hipStream_t stream) {
    const float* hs = (const float*)d_in[0];
    // d_in[1] attention_mask: zeros, unused (matches reference)
    const float* Wq = (const float*)d_in[2];
    const float* bq = (const float*)d_in[3];
    const float* Wk = (const float*)d_in[4];
    const float* bk = (const float*)d_in[5];
    const float* Wv = (const float*)d_in[6];
    const float* bv = (const float*)d_in[7];
    float* out = (float*)d_out;

    bf16* Xb    = (bf16*)d_ws;                            // 8192*768
    bf16* Wt    = Xb + (size_t)8192 * 768;                // 3*768*768 (transposed)
    bf16* QKV   = Wt + (size_t)3 * 768 * 768;             // Q,K:[B,H,S,DH]; V:[B,H,DH,S]
    bf16* Opart = QKV + (size_t)3 * B_ * H_ * S_ * DH_;   // 1920*8192 bf16
    float* Lpart = (float*)(Opart + (size_t)1920 * 8192); // 1920*128 f32

    cvt_f32_bf16<<<6144, 256, 0, stream>>>(hs, Xb, 1572864);
    w_transpose<<<dim3(12, 12, 3), 256, 0, stream>>>(Wq, Wk, Wv, Wt);
    qkv_gemm<<<dim3(64, 6, 3), 256, 0, stream>>>(Xb, Wt, bq, bk, bv, QKV);
    attn_chunk<<<dim3(40, 48), 256, 0, stream>>>(QKV, out, Opart, Lpart);
    attn_reduce<<<dim3(12, 48), 256, 0, stream>>>(Opart, Lpart, out);
}

// Round 9
// 202.456 us; speedup vs baseline: 1.0205x; 1.0205x over previous
//
#include <hip/hip_runtime.h>
#include <hip/hip_bf16.h>

#define B_  4
#define S_  2048
#define D_  768
#define H_  12
#define DH_ 64

typedef __bf16 bf16;
typedef __attribute__((ext_vector_type(8))) __bf16 bf16x8;
typedef __attribute__((ext_vector_type(4))) __bf16 bf16x4;
typedef __attribute__((ext_vector_type(4))) float floatx4;
typedef __attribute__((ext_vector_type(16))) float floatx16;

__device__ __forceinline__ void load_lds16(const bf16* g, bf16* l) {
    __builtin_amdgcn_global_load_lds((const __attribute__((address_space(1))) void*)g,
                                     (__attribute__((address_space(3))) void*)l, 16, 0, 0);
}

// pack two f32 -> packed bf16 pair (round-half-up: bias + v_perm, 3 ops)
__device__ __forceinline__ unsigned pack2(float a, float b) {
    unsigned ua = __builtin_bit_cast(unsigned, a) + 0x8000u;
    unsigned ub = __builtin_bit_cast(unsigned, b) + 0x8000u;
    return __builtin_amdgcn_perm(ub, ua, 0x07060302);
}

// 128-row q-tiles (qt2 0..15); kt-tiles of 64 keys, chunks of <=8 kt-tiles.
__device__ __forceinline__ int chunk_off2(int qt2) {
    if (qt2 < 4)  return qt2;
    if (qt2 < 8)  return 4 + 2 * (qt2 - 4);
    if (qt2 < 12) return 12 + 3 * (qt2 - 8);
    return 24 + 4 * (qt2 - 12);
}

// ---------------- prep: fp32->bf16 cvt + W transpose, one launch ----------
__global__ __launch_bounds__(256) void prep(const float* __restrict__ hs,
                                            const float* __restrict__ w0,
                                            const float* __restrict__ w1,
                                            const float* __restrict__ w2,
                                            bf16* __restrict__ Xb,
                                            bf16* __restrict__ Wt)
{
    __shared__ bf16 t[64 * 72];
    const int bx = blockIdx.x;
    const int tid = threadIdx.x;
    if (bx < 6144) {   // cvt: hidden_states -> bf16
        int i = bx * 256 + tid;
        float4 v = ((const float4*)hs)[i];
        bf16x4 o;
        o[0] = (bf16)v.x; o[1] = (bf16)v.y; o[2] = (bf16)v.z; o[3] = (bf16)v.w;
        *(bf16x4*)(Xb + (size_t)i * 4) = o;
        return;
    }
    // W transpose: W[k][n] f32 -> Wt[n][k] bf16
    const int tb = bx - 6144;            // 0..431
    const int which = tb / 144;
    const int rest = tb % 144;
    const int k0 = (rest / 12) * 64, n0 = (rest % 12) * 64;
    const float* W = (which == 0) ? w0 : (which == 1 ? w1 : w2);
    bf16* dst = Wt + (size_t)which * D_ * D_;
    {
        int r = tid >> 2;
        int c0 = (tid & 3) * 16;
        #pragma unroll
        for (int q = 0; q < 4; q++) {
            float4 v = *(const float4*)(W + (size_t)(k0 + r) * D_ + n0 + c0 + q * 4);
            t[(c0 + q * 4 + 0) * 72 + r] = (bf16)v.x;
            t[(c0 + q * 4 + 1) * 72 + r] = (bf16)v.y;
            t[(c0 + q * 4 + 2) * 72 + r] = (bf16)v.z;
            t[(c0 + q * 4 + 3) * 72 + r] = (bf16)v.w;
        }
    }
    __syncthreads();
    {
        int n = tid >> 3, seg = tid & 7;
        *(bf16x8*)(dst + (size_t)(n0 + n) * D_ + k0 + seg * 8) =
            *(const bf16x8*)(t + n * 72 + seg * 8);
        *(bf16x8*)(dst + (size_t)(n0 + n + 32) * D_ + k0 + seg * 8) =
            *(const bf16x8*)(t + (n + 32) * 72 + seg * 8);
    }
}

// ---------------- QKV projection GEMM ----------------
// 128x128 tile, 32x32x16 MFMA, BK=32 double-buffered global_load_lds DMA
// (32 KB LDS total -> 5 blocks/CU). One barrier per iter; the vmcnt(0) drain
// waits on DMA issued a full compute phase earlier. Chunk-rotation swizzle
// cpos=(gc+(row>>1))&3 : DMA stays lane-linear+coalesced, frag reads 2-way.
__global__ __launch_bounds__(256) void qkv_gemm(
    const bf16* __restrict__ Xb, const bf16* __restrict__ Wt,
    const float* __restrict__ bq, const float* __restrict__ bk,
    const float* __restrict__ bv, bf16* __restrict__ QKV)
{
    const int which = blockIdx.z;
    const bf16* Wm = Wt + (size_t)which * D_ * D_;
    const float* bias = (which == 0) ? bq : (which == 1 ? bk : bv);
    bf16* out = QKV + (size_t)which * B_ * H_ * S_ * DH_;

    __shared__ bf16 As[2][128 * 32];   // 8 KB per buffer
    __shared__ bf16 Bs[2][128 * 32];

    const int tid  = threadIdx.x;
    const int wave = tid >> 6, lane = tid & 63;
    const int wr = wave >> 1, wc = wave & 1;
    const int l31 = lane & 31, lh = lane >> 5;
    const int m0 = blockIdx.x * 128, n0 = blockIdx.y * 128;

    // DMA chunk map: 512 16B-chunks per matrix, 2/thread; lane-linear LDS dst
    const bf16 *ga_[2], *gb_[2];
    int lds_[2];
    #pragma unroll
    for (int i = 0; i < 2; i++) {
        int fc = i * 256 + tid;
        int row = fc >> 2, cpos = fc & 3;
        int gc = (cpos - (row >> 1)) & 3;          // inverse rotation
        ga_[i] = Xb + (size_t)(m0 + row) * D_ + gc * 8;
        gb_[i] = Wm + (size_t)(n0 + row) * D_ + gc * 8;
        lds_[i] = fc * 8;
    }

    floatx16 acc[2][2];
    #pragma unroll
    for (int mt = 0; mt < 2; mt++)
        #pragma unroll
        for (int nt = 0; nt < 2; nt++)
            #pragma unroll
            for (int e = 0; e < 16; e++) acc[mt][nt][e] = 0.f;

    // prologue: stage k0=0 into buffer 0
    #pragma unroll
    for (int i = 0; i < 2; i++) {
        load_lds16(ga_[i], &As[0][lds_[i]]);
        load_lds16(gb_[i], &Bs[0][lds_[i]]);
    }

    const int cp = (l31 >> 1) & 3;
    for (int it = 0; it < 24; ++it) {
        const int cur = it & 1;
        __syncthreads();   // drains DMA into buf[cur] (issued 1 iter ago)
        if (it + 1 < 24) {
            const int kn = (it + 1) * 32;
            #pragma unroll
            for (int i = 0; i < 2; i++) {
                load_lds16(ga_[i] + kn, &As[cur ^ 1][lds_[i]]);
                load_lds16(gb_[i] + kn, &Bs[cur ^ 1][lds_[i]]);
            }
        }
        const bf16* Ac = As[cur];
        const bf16* Bc = Bs[cur];
        #pragma unroll
        for (int s = 0; s < 2; s++) {
            const int off = ((2 * s + lh + cp) & 3) * 8;
            bf16x8 af[2], bfr[2];
            #pragma unroll
            for (int mt = 0; mt < 2; mt++)
                af[mt] = *(const bf16x8*)(Ac + (wr * 64 + mt * 32 + l31) * 32 + off);
            #pragma unroll
            for (int nt = 0; nt < 2; nt++)
                bfr[nt] = *(const bf16x8*)(Bc + (wc * 64 + nt * 32 + l31) * 32 + off);
            #pragma unroll
            for (int mt = 0; mt < 2; mt++)
                #pragma unroll
                for (int nt = 0; nt < 2; nt++)
                    acc[mt][nt] = __builtin_amdgcn_mfma_f32_32x32x16_bf16(
                        af[mt], bfr[nt], acc[mt][nt], 0, 0, 0);
        }
    }

    // Epilogue. 32x32 C layout: col=l31, row = rr + 8*rq + 4*lh (reg=4rq+rr).
    const float sc = (which == 0) ? 0.125f : 1.0f;   // fold 1/sqrt(DH) into Q
    #pragma unroll
    for (int mt = 0; mt < 2; mt++) {
        #pragma unroll
        for (int nt = 0; nt < 2; nt++) {
            const int n = n0 + wc * 64 + nt * 32 + l31;
            const float bv_ = bias[n];
            const int h = n >> 6, dh = n & 63;
            const int mb = m0 + wr * 64 + mt * 32 + 4 * lh;
            #pragma unroll
            for (int rq = 0; rq < 4; rq++) {
                const int m = mb + 8 * rq;
                const int b = m >> 11, s0 = m & 2047;
                if (which == 2) {
                    bf16x4 o;
                    #pragma unroll
                    for (int rr = 0; rr < 4; rr++) o[rr] = (bf16)(acc[mt][nt][4 * rq + rr] + bv_);
                    *(bf16x4*)(out + ((size_t)((b * H_ + h) * DH_ + dh)) * S_ + s0) = o;
                } else {
                    #pragma unroll
                    for (int rr = 0; rr < 4; rr++)
                        out[(((size_t)(b * H_ + h) * S_ + s0 + rr) << 6) + dh] =
                            (bf16)((acc[mt][nt][4 * rq + rr] + bv_) * sc);
                }
            }
        }
    }
}

// ---------------- Flash attention (r7 structure: padded LDS, VGPR prefetch) -
// 32x32x16 MFMA, O^T = V^T P^T per 32-q wave slice, fixed-max softmax,
// sequential kk tiles, wave-uniform mask branch, v_perm pack, split L sums.
__global__ __launch_bounds__(256, 3) void attn_chunk(const bf16* __restrict__ QKV,
                                                     float* __restrict__ out,
                                                     bf16* __restrict__ Opart,
                                                     float* __restrict__ Lpart)
{
    const int cid = 39 - blockIdx.x;   // heavy q-tiles dispatch first
    const int bh = blockIdx.y;
    const int b = bh / H_, h = bh % H_;

    int qt2, c;
    if (cid < 4)       { qt2 = cid; c = 0; }
    else if (cid < 12) { int t = cid - 4;  qt2 = 4 + (t >> 1);  c = t & 1; }
    else if (cid < 24) { int t = cid - 12; qt2 = 8 + t / 3;     c = t - 3 * (t / 3); }
    else               { int t = cid - 24; qt2 = 12 + (t >> 2); c = t & 3; }
    const int nch = (2 * qt2 + 9) >> 3;
    const int kt0 = c * 8;
    const int kt1 = min(kt0 + 7, 2 * qt2 + 1);

    const size_t MAT = (size_t)B_ * H_ * S_ * DH_;
    const bf16* Q  = QKV +           (size_t)bh * S_ * DH_;  // [s][dh], pre-scaled 1/8
    const bf16* K  = QKV + MAT +     (size_t)bh * S_ * DH_;  // [s][dh]
    const bf16* Vt = QKV + 2 * MAT + (size_t)bh * S_ * DH_;  // [dh][s]

    __shared__ bf16 Ks[64 * 72];    // [key][dh]
    __shared__ bf16 Vts[64 * 72];   // [dh][key]

    const int tid  = threadIdx.x;
    const int wave = tid >> 6, lane = tid & 63;
    const int l31 = lane & 31, lh = lane >> 5;
    const int srow = tid >> 3, sseg = tid & 7;
    const int qbase = qt2 * 128;
    const int qs = qbase + wave * 32;     // wave's 32-q slice
    const int q = qs + l31;               // this lane's q column

    // Q B-frags for all 4 ksteps, persistent across the kt loop.
    bf16x8 qf[4];
    {
        const bf16* qrow = Q + (size_t)q * DH_ + lh * 8;
        #pragma unroll
        for (int s = 0; s < 4; s++) qf[s] = *(const bf16x8*)(qrow + s * 16);
    }

    floatx16 accO[2];   // O^T: dh-tile dt -> rows dt*32+rho, col q
    #pragma unroll
    for (int dt = 0; dt < 2; dt++)
        #pragma unroll
        for (int e = 0; e < 16; e++) accO[dt][e] = 0.f;
    float lsum[4] = {0.f, 0.f, 0.f, 0.f};   // 4 independent add chains

    const bf16* kptr = K  + (size_t)(kt0 * 64 + srow) * DH_ + sseg * 8;
    const bf16* vptr = Vt + (size_t)srow * S_ + kt0 * 64 + sseg * 8;
    bf16x8 ka = *(const bf16x8*)kptr;
    bf16x8 kb = *(const bf16x8*)(kptr + 32 * DH_);
    bf16x8 va = *(const bf16x8*)vptr;
    bf16x8 vb = *(const bf16x8*)(vptr + (size_t)32 * S_);

    for (int kt = kt0; kt <= kt1; ++kt) {
        __syncthreads();
        *(bf16x8*)(Ks  + srow * 72 + sseg * 8) = ka;
        *(bf16x8*)(Ks  + (srow + 32) * 72 + sseg * 8) = kb;
        *(bf16x8*)(Vts + srow * 72 + sseg * 8) = va;
        *(bf16x8*)(Vts + (srow + 32) * 72 + sseg * 8) = vb;
        __syncthreads();
        if (kt < kt1) {
            kptr += 64 * DH_;
            vptr += 64;
            ka = *(const bf16x8*)kptr;
            kb = *(const bf16x8*)(kptr + 32 * DH_);
            va = *(const bf16x8*)vptr;
            vb = *(const bf16x8*)(vptr + (size_t)32 * S_);
        }

        const bool domask = (kt * 64 + 63 > qs);   // wave-uniform

        #pragma unroll
        for (int kk = 0; kk < 2; kk++) {
            // S^T = K Q^T for this 32-key tile
            floatx16 accS;
            #pragma unroll
            for (int e = 0; e < 16; e++) accS[e] = 0.f;
            #pragma unroll
            for (int s = 0; s < 4; s++) {
                bf16x8 kf = *(const bf16x8*)(Ks + (kk * 32 + l31) * 72 + s * 16 + lh * 8);
                accS = __builtin_amdgcn_mfma_f32_32x32x16_bf16(kf, qf[s], accS, 0, 0, 0);
            }

            // p = exp(s); pack to bf16 pairs; mask only on diagonal tiles
            unsigned pk1[4], pk2[4];
            if (domask) {
                const int keyb = kt * 64 + kk * 32 + 4 * lh;
                #pragma unroll
                for (int rq = 0; rq < 4; rq++) {
                    float p[4];
                    #pragma unroll
                    for (int rr = 0; rr < 4; rr++) {
                        float v = __expf(accS[4 * rq + rr]);
                        if (keyb + 8 * rq + rr > q) v = 0.f;
                        p[rr] = v;
                        lsum[rq] += v;
                    }
                    pk1[rq] = pack2(p[0], p[1]);
                    pk2[rq] = pack2(p[2], p[3]);
                }
            } else {
                #pragma unroll
                for (int rq = 0; rq < 4; rq++) {
                    float p[4];
                    #pragma unroll
                    for (int rr = 0; rr < 4; rr++) {
                        float v = __expf(accS[4 * rq + rr]);
                        p[rr] = v;
                        lsum[rq] += v;
                    }
                    pk1[rq] = pack2(p[0], p[1]);
                    pk2[rq] = pack2(p[2], p[3]);
                }
            }

            // PV for this kk's two ksteps: C->B-frag via shfl_xor(32)+selects
            #pragma unroll
            for (int sl = 0; sl < 2; sl++) {
                const int s = kk * 2 + sl;
                unsigned sendA = lh ? pk1[2 * sl] : pk1[2 * sl + 1];
                unsigned sendB = lh ? pk2[2 * sl] : pk2[2 * sl + 1];
                unsigned recvA = __shfl_xor(sendA, 32, 64);
                unsigned recvB = __shfl_xor(sendB, 32, 64);
                uint4 w;
                w.x = lh ? recvA : pk1[2 * sl];
                w.y = lh ? recvB : pk2[2 * sl];
                w.z = lh ? pk1[2 * sl + 1] : recvA;
                w.w = lh ? pk2[2 * sl + 1] : recvB;
                bf16x8 ptf = __builtin_bit_cast(bf16x8, w);
                #pragma unroll
                for (int dt = 0; dt < 2; dt++) {
                    bf16x8 vf = *(const bf16x8*)(Vts + (dt * 32 + l31) * 72 + s * 16 + lh * 8);
                    accO[dt] = __builtin_amdgcn_mfma_f32_32x32x16_bf16(vf, ptf, accO[dt], 0, 0, 0);
                }
            }
        }
    }

    // complete the row sum: own half + partner half
    const float Lr = (lsum[0] + lsum[1]) + (lsum[2] + lsum[3]);
    const float L = Lr + __shfl_xor(Lr, 32, 64);

    if (nch == 1) {
        const float inv = 1.0f / L;
        float* orow = out + (size_t)(b * S_ + q) * D_ + h * DH_;
        #pragma unroll
        for (int dt = 0; dt < 2; dt++)
            #pragma unroll
            for (int rq = 0; rq < 4; rq++) {
                float4 o;
                o.x = accO[dt][4 * rq + 0] * inv; o.y = accO[dt][4 * rq + 1] * inv;
                o.z = accO[dt][4 * rq + 2] * inv; o.w = accO[dt][4 * rq + 3] * inv;
                *(float4*)(orow + dt * 32 + 8 * rq + 4 * lh) = o;
            }
    } else {
        const int chunk = bh * 40 + chunk_off2(qt2) + c;
        bf16* obase = Opart + (size_t)chunk * 8192 + (wave * 32 + l31) * 64;
        #pragma unroll
        for (int dt = 0; dt < 2; dt++)
            #pragma unroll
            for (int rq = 0; rq < 4; rq++) {
                bf16x4 o;
                #pragma unroll
                for (int rr = 0; rr < 4; rr++) o[rr] = (bf16)accO[dt][4 * rq + rr];
                *(bf16x4*)(obase + dt * 32 + 8 * rq + 4 * lh) = o;
            }
        if (lh == 0) Lpart[chunk * 128 + wave * 32 + l31] = L;
    }
}

// ---------------- reduce: sum chunk partials, normalize, write out ----------
__global__ __launch_bounds__(256) void attn_reduce(const bf16* __restrict__ Opart,
                                                   const float* __restrict__ Lpart,
                                                   float* __restrict__ out)
{
    const int qt2 = 4 + blockIdx.x;   // 4..15
    const int bh = blockIdx.y;
    const int b = bh / H_, h = bh % H_;
    const int nch = (2 * qt2 + 9) >> 3;   // 2..4
    const int cb = bh * 40 + chunk_off2(qt2);

    const int e = threadIdx.x;
    const int ql = e >> 1, dh0 = (e & 1) * 32;

    float o[32];
    #pragma unroll
    for (int i = 0; i < 32; i++) o[i] = 0.f;
    float l = 0.f;

    for (int cidx = 0; cidx < nch; cidx++) {
        const bf16* p = Opart + (size_t)(cb + cidx) * 8192 + ql * 64 + dh0;
        #pragma unroll
        for (int m = 0; m < 4; m++) {
            bf16x8 v = *(const bf16x8*)(p + m * 8);
            #pragma unroll
            for (int k = 0; k < 8; k++) o[m * 8 + k] += (float)v[k];
        }
        l += Lpart[(cb + cidx) * 128 + ql];
    }
    float inv = 1.0f / l;
    float* orow = out + (size_t)(b * S_ + qt2 * 128 + ql) * D_ + h * DH_ + dh0;
    #pragma unroll
    for (int m = 0; m < 8; m++) {
        float4 v;
        v.x = o[m * 4 + 0] * inv; v.y = o[m * 4 + 1] * inv;
        v.z = o[m * 4 + 2] * inv; v.w = o[m * 4 + 3] * inv;
        *(float4*)(orow + m * 4) = v;
    }
}

extern "C" void kernel_launch(void* const* d_in, const int* in_sizes, int n_in,
                              void* d_out, int out_size, void* d_ws, size_t ws_size,
                              hipStream_t stream) {
    const float* hs = (const float*)d_in[0];
    // d_in[1] attention_mask: zeros, unused (matches reference)
    const float* Wq = (const float*)d_in[2];
    const float* bq = (const float*)d_in[3];
    const float* Wk = (const float*)d_in[4];
    const float* bk = (const float*)d_in[5];
    const float* Wv = (const float*)d_in[6];
    const float* bv = (const float*)d_in[7];
    float* out = (float*)d_out;

    bf16* Xb    = (bf16*)d_ws;                            // 8192*768
    bf16* Wt    = Xb + (size_t)8192 * 768;                // 3*768*768 (transposed)
    bf16* QKV   = Wt + (size_t)3 * 768 * 768;             // Q,K:[B,H,S,DH]; V:[B,H,DH,S]
    bf16* Opart = QKV + (size_t)3 * B_ * H_ * S_ * DH_;   // 1920*8192 bf16
    float* Lpart = (float*)(Opart + (size_t)1920 * 8192); // 1920*128 f32

    prep<<<6576, 256, 0, stream>>>(hs, Wq, Wk, Wv, Xb, Wt);
    qkv_gemm<<<dim3(64, 6, 3), 256, 0, stream>>>(Xb, Wt, bq, bk, bv, QKV);
    attn_chunk<<<dim3(40, 48), 256, 0, stream>>>(QKV, out, Opart, Lpart);
    attn_reduce<<<dim3(12, 48), 256, 0, stream>>>(Opart, Lpart, out);
}